// Round 2
// baseline (658.632 us; speedup 1.0000x reference)
//
#include <hip/hip_runtime.h>
#include <stdint.h>

#define NN 256
#define BATCH 262144

typedef unsigned short ushort_t;
typedef __attribute__((ext_vector_type(8))) short short8_t;
typedef __attribute__((ext_vector_type(4))) float f32x4;

__device__ __forceinline__ ushort_t f2bf(float f) {
  // round-to-nearest-even float -> bf16 (finite values only)
  uint32_t u = __float_as_uint(f);
  u += 0x7fffu + ((u >> 16) & 1u);
  return (ushort_t)(u >> 16);
}

// ---------------- K1: M = W^T W (fp32) ----------------
__global__ __launch_bounds__(256) void gram_kernel(const float* __restrict__ W,
                                                   float* __restrict__ M) {
  int bi = blockIdx.x >> 4, bj = blockIdx.x & 15;
  int ti = threadIdx.x >> 4, tj = threadIdx.x & 15;
  int i = bi * 16 + ti, j = bj * 16 + tj;
  float acc = 0.f;
#pragma unroll 8
  for (int k = 0; k < NN; ++k) acc += W[k * NN + i] * W[k * NN + j];
  M[i * NN + j] = acc;
}

// ---------------- K2: v = M^20 v0 ; sigma = sqrt(v^T M v / v^T v); emit Wz ----------------
// M rows live in registers (1024 threads = 256 rows x 4 col-chunks, 16 f32x4 each).
// Wz emitted PLAIN row-major bf16: wz[n*NN + k] = (n==k ? 0 : W[n][k]/sigma)
__global__ __launch_bounds__(1024) void power_kernel(const float* __restrict__ W,
                                                     const float* __restrict__ M,
                                                     ushort_t* __restrict__ wz) {
  __shared__ float v_lds[NN];
  __shared__ float psum[4 * NN];
  __shared__ float red[16];
  __shared__ float scale_s;
  const int t = threadIdx.x;
  const int r = t >> 2, qc = t & 3;  // thread owns M[r][j*16 + qc*4 .. +3], j=0..15

  f32x4 Mreg[16];
#pragma unroll
  for (int j = 0; j < 16; ++j)
    Mreg[j] = *(const f32x4*)(M + r * NN + j * 16 + qc * 4);

  if (t < NN) v_lds[t] = 0.0625f;  // 1/sqrt(256)
  __syncthreads();

  // 20 matvecs (unnormalized; direction-identical to per-step normalization),
  // 21st matvec produces y = M v_hat for sigma^2 = v.y / v.v
  for (int it = 0; it < 21; ++it) {
    float p = 0.f;
#pragma unroll
    for (int j = 0; j < 16; ++j) {
      f32x4 v4 = *(const f32x4*)(v_lds + j * 16 + qc * 4);
      p += Mreg[j].x * v4.x + Mreg[j].y * v4.y + Mreg[j].z * v4.z + Mreg[j].w * v4.w;
    }
    psum[qc * NN + r] = p;
    __syncthreads();
    if (it < 20) {
      if (t < NN)
        v_lds[t] = psum[t] + psum[NN + t] + psum[2 * NN + t] + psum[3 * NN + t];
      __syncthreads();
    }
  }

  float num = 0.f, den = 0.f;
  if (t < NN) {
    float y = psum[t] + psum[NN + t] + psum[2 * NN + t] + psum[3 * NN + t];
    float v = v_lds[t];
    num = v * y;
    den = v * v;
  }
#pragma unroll
  for (int off = 32; off > 0; off >>= 1) {
    num += __shfl_down(num, off);
    den += __shfl_down(den, off);
  }
  if (t < NN && (t & 63) == 0) {
    red[(t >> 6) * 2] = num;
    red[(t >> 6) * 2 + 1] = den;
  }
  __syncthreads();
  if (t == 0) {
    float n = red[0] + red[2] + red[4] + red[6];
    float d = red[1] + red[3] + red[5] + red[7];
    float sig = sqrtf(n / d) + 1e-12f;
    scale_s = 1.0f / sig;  // LIP_CONSTANT = 1
  }
  __syncthreads();
  const float scale = scale_s;

  for (int o = t; o < 8192; o += 1024) {
    int n = o >> 5;
    int k0 = (o & 31) * 8;
    f32x4 a = *(const f32x4*)(W + n * NN + k0);
    f32x4 b = *(const f32x4*)(W + n * NN + k0 + 4);
    float f[8] = {a.x, a.y, a.z, a.w, b.x, b.y, b.z, b.w};
    short8_t pack;
#pragma unroll
    for (int e = 0; e < 8; ++e) {
      float val = (n == k0 + e) ? 0.f : f[e] * scale;
      pack[e] = (short)f2bf(val);
    }
    *(short8_t*)(wz + n * NN + k0) = pack;
  }
}

// ---------------- K3: out = x @ Wz^T  (bf16 MFMA, fp32 out, NO LDS) ----------------
// BM=64, BN=256. 256 threads / 4 waves; wave w owns cols w*64..w*64+63.
// Each lane loads its MFMA fragments straight from global:
//   A-frag(mt): 32B of x[m0+mt*16+m][kt*32+q*8..], converted fp32->bf16 in-reg
//   B-frag(nt): 16B of wz[(w*64+nt*16+m)*NN + kt*32+q*8]  (L2-resident, 128 KB)
// No __syncthreads, no LDS, no staging.
__global__ __launch_bounds__(256, 4) void gemm_kernel(const float* __restrict__ x,
                                                      const ushort_t* __restrict__ wz,
                                                      float* __restrict__ out) {
  const int tid = threadIdx.x;
  const int wave = tid >> 6, lane = tid & 63;
  const int m = lane & 15, q = lane >> 4;
  const int m0 = blockIdx.x * 64;

  f32x4 acc[4][4];
  const f32x4 zero = {0.f, 0.f, 0.f, 0.f};
#pragma unroll
  for (int a = 0; a < 4; ++a)
#pragma unroll
    for (int b = 0; b < 4; ++b) acc[a][b] = zero;

  const float* xbase = x + (m0 + m) * NN + q * 8;
  const ushort_t* wbase = wz + (wave * 64 + m) * NN + q * 8;

  for (int kt = 0; kt < 8; ++kt) {
    short8_t bfrag[4];
#pragma unroll
    for (int nt = 0; nt < 4; ++nt)
      bfrag[nt] = *(const short8_t*)(wbase + nt * 16 * NN + kt * 32);

    short8_t af[4];
#pragma unroll
    for (int mt = 0; mt < 4; ++mt) {
      const float* p = xbase + (mt * 16) * NN + kt * 32;
      f32x4 a0 = __builtin_nontemporal_load((const f32x4*)p);
      f32x4 a1 = __builtin_nontemporal_load((const f32x4*)(p + 4));
      short8_t av;
      av[0] = (short)f2bf(a0.x); av[1] = (short)f2bf(a0.y);
      av[2] = (short)f2bf(a0.z); av[3] = (short)f2bf(a0.w);
      av[4] = (short)f2bf(a1.x); av[5] = (short)f2bf(a1.y);
      av[6] = (short)f2bf(a1.z); av[7] = (short)f2bf(a1.w);
      af[mt] = av;
    }

#pragma unroll
    for (int mt = 0; mt < 4; ++mt)
#pragma unroll
      for (int nt = 0; nt < 4; ++nt)
        acc[mt][nt] = __builtin_amdgcn_mfma_f32_16x16x32_bf16(af[mt], bfrag[nt],
                                                              acc[mt][nt], 0, 0, 0);
  }

  // epilogue: C/D layout col=lane&15, row=q*4+e
#pragma unroll
  for (int mt = 0; mt < 4; ++mt) {
#pragma unroll
    for (int nt = 0; nt < 4; ++nt) {
      const int col = wave * 64 + nt * 16 + m;
      const int rowb = m0 + mt * 16 + q * 4;
#pragma unroll
      for (int e = 0; e < 4; ++e)
        __builtin_nontemporal_store(acc[mt][nt][e], out + (rowb + e) * NN + col);
    }
  }
}

extern "C" void kernel_launch(void* const* d_in, const int* in_sizes, int n_in,
                              void* d_out, int out_size, void* d_ws, size_t ws_size,
                              hipStream_t stream) {
  const float* x = (const float*)d_in[0];
  const float* W = (const float*)d_in[1];
  float* out = (float*)d_out;

  char* ws = (char*)d_ws;
  ushort_t* wz = (ushort_t*)ws;            // 131072 B, plain row-major bf16 Wz
  float* M = (float*)(ws + 131072);        // 262144 B, M = W^T W

  gram_kernel<<<256, 256, 0, stream>>>(W, M);
  power_kernel<<<1, 1024, 0, stream>>>(W, M, wz);
  gemm_kernel<<<BATCH / 64, 256, 0, stream>>>(x, wz, out);
}